// Round 24
// baseline (5735.135 us; speedup 1.0000x reference)
//
#include <hip/hip_runtime.h>

// T=512, B=64, D=1024, H=2048, L=256
// d_out (f32): recon[65536] | recon_seq[512*64*1024] | latent_seq[512*64*256] | spike_rate[3] | recon_err[1]
//
// VERIFIED reference model (r22 PASS): all GEMMs = ascending-k fmaf chains,
// K-block 512 (left-fold, one rounded add per boundary), bias separate f32
// add; LIF: V = fmaf(0.9, V, I); s = (V-1>0); V -= s.
// Round 24 (perf): 128x128 tile, 8x8/thread with CONFLICT-FREE 4+4 split
// mapping (rows ty*4/64+ty*4, cols tx*4/64+tx*4 -> broadcast or 2-way reads),
// BK=16, r22-style single-buffer 2-barrier loop. Fold at kt%32 (k%512).

#define T_STEPS 512
#define BB 64
#define DD 1024
#define HH 2048
#define LL 256

// ---------------------------------------------------------------------------
// Panel GEMM, KC=512 fixed, remainder-last, left-fold: C = A@B + bias.
// A float or uchar(0/1). 128x128 tile, BK=16, 256 threads, 8x8 per thread.
// M%128==0, N%128==0, K%16==0 (K in {256,1024,2048}).
// ---------------------------------------------------------------------------
template<typename AT>
__global__ __launch_bounds__(256) void gemm_panel(
    const AT* __restrict__ A, const float* __restrict__ Bm,
    const float* __restrict__ bias, float* __restrict__ C,
    int M, int N, int K)
{
  __shared__ float As[16][128];
  __shared__ float Bs[16][128];
  const int tid = threadIdx.x;
  const int tx = tid & 15, ty = tid >> 4;
  const int row0 = blockIdx.y * 128, col0 = blockIdx.x * 128;
  const int lar = tid >> 1;              // A row 0..127
  const int lak = (tid & 1) * 8;         // A k-offset 0 or 8
  const int lbk = tid >> 4;              // B k-row 0..15
  const int lbn = (tid & 15) * 8;        // B col 0,8,...,120

  float acc[8][8] = {};    // folded panels
  float pacc[8][8] = {};   // current panel (ascending-k FMA chain)
  const int KT = K >> 4;

  float a8[8];
  float4 b40, b41;
  auto fetch = [&](int kt) {
    if constexpr (sizeof(AT) == 1) {
      unsigned long long w =
          *(const unsigned long long*)(A + (size_t)(row0 + lar) * K + kt * 16 + lak);
      #pragma unroll
      for (int j = 0; j < 8; ++j) a8[j] = (float)((w >> (8 * j)) & 0xFFull);
    } else {
      const float* ap = (const float*)A + (size_t)(row0 + lar) * K + kt * 16 + lak;
      float4 f0 = *(const float4*)ap;
      float4 f1 = *(const float4*)(ap + 4);
      a8[0] = f0.x; a8[1] = f0.y; a8[2] = f0.z; a8[3] = f0.w;
      a8[4] = f1.x; a8[5] = f1.y; a8[6] = f1.z; a8[7] = f1.w;
    }
    const float* bp = Bm + (size_t)(kt * 16 + lbk) * N + col0 + lbn;
    b40 = *(const float4*)bp;
    b41 = *(const float4*)(bp + 4);
  };

  fetch(0);
  for (int kt = 0; kt < KT; ++kt) {
    if (kt > 0 && (kt & 31) == 0) {      // panel boundary (k%512==0): fold
      #pragma unroll
      for (int i = 0; i < 8; ++i)
        #pragma unroll
        for (int j = 0; j < 8; ++j) {
          acc[i][j] = __fadd_rn(acc[i][j], pacc[i][j]);
          pacc[i][j] = 0.0f;
        }
    }
    // stage current tile
    #pragma unroll
    for (int j = 0; j < 8; ++j) As[lak + j][lar] = a8[j];
    *(float4*)&Bs[lbk][lbn] = b40;
    *(float4*)&Bs[lbk][lbn + 4] = b41;
    __syncthreads();
    if (kt + 1 < KT) fetch(kt + 1);
    #pragma unroll
    for (int k = 0; k < 16; ++k) {       // global k ascending within panel
      float av[8], bv[8];
      *(float4*)&av[0] = *(const float4*)&As[k][ty * 4];        // broadcast
      *(float4*)&av[4] = *(const float4*)&As[k][64 + ty * 4];
      *(float4*)&bv[0] = *(const float4*)&Bs[k][tx * 4];        // <=2-way
      *(float4*)&bv[4] = *(const float4*)&Bs[k][64 + tx * 4];
      #pragma unroll
      for (int i = 0; i < 8; ++i)
        #pragma unroll
        for (int j = 0; j < 8; ++j)
          pacc[i][j] = fmaf(av[i], bv[j], pacc[i][j]);
    }
    __syncthreads();
  }

  float bb[8];
  *(float4*)&bb[0] = *(const float4*)&bias[col0 + tx * 4];
  *(float4*)&bb[4] = *(const float4*)&bias[col0 + 64 + tx * 4];
  #pragma unroll
  for (int i = 0; i < 8; ++i) {
    const int r = (i < 4) ? (ty * 4 + i) : (64 + ty * 4 + i - 4);
    float o[8];
    #pragma unroll
    for (int j = 0; j < 8; ++j) {
      float tot = __fadd_rn(acc[i][j], pacc[i][j]);   // final fold
      o[j] = __fadd_rn(tot, bb[j]);                   // "+ b" (b==0)
    }
    const size_t base = (size_t)(row0 + r) * N + col0;
    *(float4*)&C[base + tx * 4] = *(const float4*)&o[0];
    *(float4*)&C[base + 64 + tx * 4] = *(const float4*)&o[4];
  }
}

// ---------------------------------------------------------------------------
// Elementwise LIF scan: v = fma(0.9f, v, I); s = (v-1>0); v -= s.
// ---------------------------------------------------------------------------
__global__ __launch_bounds__(256) void lif_scan(
    const float* __restrict__ I, float* __restrict__ V,
    unsigned char* __restrict__ S, float* __restrict__ latent,
    unsigned long long* __restrict__ cnt, int Tc, int NTOT)
{
  const int idx = blockIdx.x * 256 + threadIdx.x;
  float v = V[idx];
  unsigned c = 0;
  for (int t = 0; t < Tc; ++t) {
    v = fmaf(0.9f, v, I[(size_t)t * NTOT + idx]);   // single rounding
    const bool s = __fsub_rn(v, 1.0f) > 0.0f;
    if (s) v = __fsub_rn(v, 1.0f);
    S[(size_t)t * NTOT + idx] = (unsigned char)s;
    if (latent) latent[(size_t)t * NTOT + idx] = s ? 1.0f : 0.0f;
    c += (unsigned)s;
  }
  V[idx] = v;
  unsigned long long cc = c;
  for (int o = 32; o; o >>= 1) cc += __shfl_down(cc, o);
  if ((threadIdx.x & 63) == 0 && cc) atomicAdd(cnt, cc);
}

// ---------------------------------------------------------------------------
__global__ __launch_bounds__(256) void recon_mean_kernel(
    const float* __restrict__ rs, float* __restrict__ out)
{
  const int idx = blockIdx.x * 256 + threadIdx.x;   // 65536 total
  double s = 0.0;
  for (int t = 0; t < T_STEPS; ++t) s += (double)rs[(size_t)t * 65536 + idx];
  out[idx] = (float)(s * (1.0 / 512.0));
}

__global__ __launch_bounds__(256) void err_kernel(
    const float* __restrict__ rs, const float* __restrict__ x,
    double* __restrict__ acc)
{
  const size_t N = (size_t)T_STEPS * BB * DD;
  double s = 0.0;
  for (size_t i = (size_t)blockIdx.x * 256 + threadIdx.x; i < N;
       i += (size_t)gridDim.x * 256)
    s += (double)fabsf(rs[i] - x[i]);
  for (int o = 32; o; o >>= 1) s += __shfl_down(s, o);
  __shared__ double wsum[4];
  if ((threadIdx.x & 63) == 0) wsum[threadIdx.x >> 6] = s;
  __syncthreads();
  if (threadIdx.x == 0) atomicAdd(acc, wsum[0] + wsum[1] + wsum[2] + wsum[3]);
}

__global__ void finalize_kernel(const double* __restrict__ acc,
                                const unsigned long long* __restrict__ cnt,
                                float* __restrict__ sr, float* __restrict__ err)
{
  if (threadIdx.x == 0) {
    sr[0] = (float)((double)cnt[0] / (512.0 * 64.0 * 2048.0));
    sr[1] = (float)((double)cnt[1] / (512.0 * 64.0 * 256.0));
    sr[2] = (float)((double)cnt[2] / (512.0 * 64.0 * 2048.0));
    err[0] = (float)(acc[0] / (512.0 * 64.0 * 1024.0));
  }
}

// ---------------------------------------------------------------------------
extern "C" void kernel_launch(void* const* d_in, const int* in_sizes, int n_in,
                              void* d_out, int out_size, void* d_ws, size_t ws_size,
                              hipStream_t stream) {
  const float* x    = (const float*)d_in[0];
  const float* Wenc = (const float*)d_in[1];
  const float* benc = (const float*)d_in[2];
  const float* Wlat = (const float*)d_in[3];
  const float* blat = (const float*)d_in[4];
  const float* Wdec = (const float*)d_in[5];
  const float* bdec = (const float*)d_in[6];
  const float* Wrec = (const float*)d_in[7];
  const float* brec = (const float*)d_in[8];

  float* out = (float*)d_out;
  float* recon     = out;
  float* recon_seq = out + 65536;
  float* latent    = recon_seq + (size_t)T_STEPS * BB * DD;
  float* sr        = latent + (size_t)T_STEPS * BB * LL;
  float* errp      = sr + 3;

  char* ws = (char*)d_ws;
  float* Ve = (float*)ws;                                   // 512 KB
  float* Vl = (float*)(ws + 524288);                        // 64 KB
  float* Vd = (float*)(ws + 589824);                        // 512 KB
  unsigned long long* cnt = (unsigned long long*)(ws + 1114112);  // 24 B
  double* errAcc = (double*)(ws + 1114136);                 // 8 B
  const size_t STATE = 1114368;

  unsigned char* Senc = (unsigned char*)(ws + STATE);       // 64 MB (Sdec overlaid)
  unsigned char* Sdec = Senc;
  const size_t Z_OFF    = STATE + 67108864;
  unsigned char* Z      = (unsigned char*)(ws + Z_OFF);     // 8 MB
  const size_t ILAT_OFF = Z_OFF + 8388608;
  float* Ilat           = (float*)(ws + ILAT_OFF);          // 32 MB
  const size_t ICH_OFF  = ILAT_OFF + 33554432;
  float* Ichunk         = (float*)(ws + ICH_OFF);           // Tc*512 KB

  int Tc = 512;
  while (Tc > 2 && ICH_OFF + (size_t)Tc * 524288 > ws_size) Tc >>= 1;

  hipMemsetAsync(ws, 0, STATE, stream);

  // Stage 1+2: encoder GEMM (K=1024, folds [512,512]) + Ve scan (FMA-LIF)
  for (int c0 = 0; c0 < T_STEPS; c0 += Tc) {
    gemm_panel<float><<<dim3(HH / 128, Tc * BB / 128), 256, 0, stream>>>(
        x + (size_t)c0 * BB * DD, Wenc, benc, Ichunk, Tc * BB, HH, DD);
    lif_scan<<<512, 256, 0, stream>>>(
        Ichunk, Ve, Senc + (size_t)c0 * BB * HH, nullptr, &cnt[0], Tc, BB * HH);
  }
  // Stage 3+4: latent GEMM (binary A, K=2048, folds [512x4]) + Vl scan
  gemm_panel<unsigned char><<<dim3(LL / 128, T_STEPS * BB / 128), 256, 0, stream>>>(
      Senc, Wlat, blat, Ilat, T_STEPS * BB, LL, HH);
  lif_scan<<<64, 256, 0, stream>>>(
      Ilat, Vl, Z, latent, &cnt[1], T_STEPS, BB * LL);
  // Stage 5+6+7: decoder GEMM (K=256, single panel) + Vd scan + recon GEMM
  for (int c0 = 0; c0 < T_STEPS; c0 += Tc) {
    gemm_panel<unsigned char><<<dim3(HH / 128, Tc * BB / 128), 256, 0, stream>>>(
        Z + (size_t)c0 * BB * LL, Wdec, bdec, Ichunk, Tc * BB, HH, LL);
    lif_scan<<<512, 256, 0, stream>>>(
        Ichunk, Vd, Sdec + (size_t)c0 * BB * HH, nullptr, &cnt[2], Tc, BB * HH);
    gemm_panel<unsigned char><<<dim3(DD / 128, Tc * BB / 128), 256, 0, stream>>>(
        Sdec + (size_t)c0 * BB * HH, Wrec, brec,
        recon_seq + (size_t)c0 * BB * DD, Tc * BB, DD, HH);
  }

  recon_mean_kernel<<<256, 256, 0, stream>>>(recon_seq, recon);
  err_kernel<<<2048, 256, 0, stream>>>(recon_seq, x, errAcc);
  finalize_kernel<<<1, 64, 0, stream>>>(errAcc, cnt, sr, errp);
}

// Round 25
// 4565.038 us; speedup vs baseline: 1.2563x; 1.2563x over previous
//
#include <hip/hip_runtime.h>

// T=512, B=64, D=1024, H=2048, L=256
// d_out (f32): recon[65536] | recon_seq[512*64*1024] | latent_seq[512*64*256] | spike_rate[3] | recon_err[1]
//
// VERIFIED reference model (r22 PASS): GEMMs = ascending-k fmaf chains,
// K-block 512, left-fold (one rounded add per boundary), bias separate f32
// add; LIF: V = fmaf(0.9, V, I); s = (V-1>0); V -= s.
// Round 25 (perf): 128x128 tile, 8x8/thread, BK=16, SINGLE accumulator;
// panel fold via global RMW: first panel stores, later panels
// C = fadd_rn(C, pacc) (same thread/address => exact left-fold), bias on
// last flush. Conflict-free 4+4 split mapping (broadcast / 2-way LDS reads).

#define T_STEPS 512
#define BB 64
#define DD 1024
#define HH 2048
#define LL 256

// ---------------------------------------------------------------------------
// Panel GEMM, KC=512, remainder-last, RMW left-fold: C = A@B + bias.
// A float or uchar(0/1). 128x128 tile, BK=16, 256 threads, 8x8 per thread.
// M%128==0, N%128==0, K%16==0 (K in {256,1024,2048}).
// ---------------------------------------------------------------------------
template<typename AT>
__global__ __launch_bounds__(256) void gemm_panel(
    const AT* __restrict__ A, const float* __restrict__ Bm,
    const float* __restrict__ bias, float* __restrict__ C,
    int M, int N, int K)
{
  __shared__ float As[16][128];
  __shared__ float Bs[16][128];
  const int tid = threadIdx.x;
  const int tx = tid & 15, ty = tid >> 4;
  const int row0 = blockIdx.y * 128, col0 = blockIdx.x * 128;
  const int lar = tid >> 1;              // A row 0..127
  const int lak = (tid & 1) * 8;         // A k-offset 0 or 8
  const int lbk = tid >> 4;              // B k-row 0..15
  const int lbn = (tid & 15) * 8;        // B col 0,8,...,120

  float pacc[8][8] = {};                 // current panel (ascending-k chain)
  const int KT = K >> 4;
  int panel = 0;

  float a8[8];
  float4 b40, b41;
  auto fetch = [&](int kt) {
    if constexpr (sizeof(AT) == 1) {
      unsigned long long w =
          *(const unsigned long long*)(A + (size_t)(row0 + lar) * K + kt * 16 + lak);
      #pragma unroll
      for (int j = 0; j < 8; ++j) a8[j] = (float)((w >> (8 * j)) & 0xFFull);
    } else {
      const float* ap = (const float*)A + (size_t)(row0 + lar) * K + kt * 16 + lak;
      float4 f0 = *(const float4*)ap;
      float4 f1 = *(const float4*)(ap + 4);
      a8[0] = f0.x; a8[1] = f0.y; a8[2] = f0.z; a8[3] = f0.w;
      a8[4] = f1.x; a8[5] = f1.y; a8[6] = f1.z; a8[7] = f1.w;
    }
    const float* bp = Bm + (size_t)(kt * 16 + lbk) * N + col0 + lbn;
    b40 = *(const float4*)bp;
    b41 = *(const float4*)(bp + 4);
  };

  // flush current panel into C (exact left-fold; bias on last flush)
  auto flush = [&](bool last) {
    #pragma unroll
    for (int i = 0; i < 8; ++i) {
      const int r = (i < 4) ? (ty * 4 + i) : (64 + ty * 4 + (i - 4));
      float* cp = C + (size_t)(row0 + r) * N + col0;
      float o[8];
      if (panel == 0) {
        #pragma unroll
        for (int j = 0; j < 8; ++j) o[j] = pacc[i][j];
      } else {
        float4 c0 = *(const float4*)(cp + tx * 4);
        float4 c1 = *(const float4*)(cp + 64 + tx * 4);
        o[0] = __fadd_rn(c0.x, pacc[i][0]); o[1] = __fadd_rn(c0.y, pacc[i][1]);
        o[2] = __fadd_rn(c0.z, pacc[i][2]); o[3] = __fadd_rn(c0.w, pacc[i][3]);
        o[4] = __fadd_rn(c1.x, pacc[i][4]); o[5] = __fadd_rn(c1.y, pacc[i][5]);
        o[6] = __fadd_rn(c1.z, pacc[i][6]); o[7] = __fadd_rn(c1.w, pacc[i][7]);
      }
      if (last) {
        float4 s0 = *(const float4*)&bias[col0 + tx * 4];
        float4 s1 = *(const float4*)&bias[col0 + 64 + tx * 4];
        o[0] = __fadd_rn(o[0], s0.x); o[1] = __fadd_rn(o[1], s0.y);
        o[2] = __fadd_rn(o[2], s0.z); o[3] = __fadd_rn(o[3], s0.w);
        o[4] = __fadd_rn(o[4], s1.x); o[5] = __fadd_rn(o[5], s1.y);
        o[6] = __fadd_rn(o[6], s1.z); o[7] = __fadd_rn(o[7], s1.w);
      }
      *(float4*)(cp + tx * 4) = *(const float4*)&o[0];
      *(float4*)(cp + 64 + tx * 4) = *(const float4*)&o[4];
      if (!last) {
        #pragma unroll
        for (int j = 0; j < 8; ++j) pacc[i][j] = 0.0f;
      }
    }
    ++panel;
  };

  fetch(0);
  for (int kt = 0; kt < KT; ++kt) {
    if (kt > 0 && (kt & 31) == 0) flush(false);   // k%512 boundary
    // stage current tile
    #pragma unroll
    for (int j = 0; j < 8; ++j) As[lak + j][lar] = a8[j];
    *(float4*)&Bs[lbk][lbn] = b40;
    *(float4*)&Bs[lbk][lbn + 4] = b41;
    __syncthreads();
    if (kt + 1 < KT) fetch(kt + 1);
    #pragma unroll
    for (int k = 0; k < 16; ++k) {       // global k ascending within panel
      float av[8], bv[8];
      *(float4*)&av[0] = *(const float4*)&As[k][ty * 4];        // broadcast
      *(float4*)&av[4] = *(const float4*)&As[k][64 + ty * 4];
      *(float4*)&bv[0] = *(const float4*)&Bs[k][tx * 4];        // <=2-way
      *(float4*)&bv[4] = *(const float4*)&Bs[k][64 + tx * 4];
      #pragma unroll
      for (int i = 0; i < 8; ++i)
        #pragma unroll
        for (int j = 0; j < 8; ++j)
          pacc[i][j] = fmaf(av[i], bv[j], pacc[i][j]);
    }
    __syncthreads();
  }
  flush(true);
}

// ---------------------------------------------------------------------------
// Elementwise LIF scan: v = fma(0.9f, v, I); s = (v-1>0); v -= s.
// ---------------------------------------------------------------------------
__global__ __launch_bounds__(256) void lif_scan(
    const float* __restrict__ I, float* __restrict__ V,
    unsigned char* __restrict__ S, float* __restrict__ latent,
    unsigned long long* __restrict__ cnt, int Tc, int NTOT)
{
  const int idx = blockIdx.x * 256 + threadIdx.x;
  float v = V[idx];
  unsigned c = 0;
  for (int t = 0; t < Tc; ++t) {
    v = fmaf(0.9f, v, I[(size_t)t * NTOT + idx]);   // single rounding
    const bool s = __fsub_rn(v, 1.0f) > 0.0f;
    if (s) v = __fsub_rn(v, 1.0f);
    S[(size_t)t * NTOT + idx] = (unsigned char)s;
    if (latent) latent[(size_t)t * NTOT + idx] = s ? 1.0f : 0.0f;
    c += (unsigned)s;
  }
  V[idx] = v;
  unsigned long long cc = c;
  for (int o = 32; o; o >>= 1) cc += __shfl_down(cc, o);
  if ((threadIdx.x & 63) == 0 && cc) atomicAdd(cnt, cc);
}

// ---------------------------------------------------------------------------
__global__ __launch_bounds__(256) void recon_mean_kernel(
    const float* __restrict__ rs, float* __restrict__ out)
{
  const int idx = blockIdx.x * 256 + threadIdx.x;   // 65536 total
  double s = 0.0;
  for (int t = 0; t < T_STEPS; ++t) s += (double)rs[(size_t)t * 65536 + idx];
  out[idx] = (float)(s * (1.0 / 512.0));
}

__global__ __launch_bounds__(256) void err_kernel(
    const float* __restrict__ rs, const float* __restrict__ x,
    double* __restrict__ acc)
{
  const size_t N = (size_t)T_STEPS * BB * DD;
  double s = 0.0;
  for (size_t i = (size_t)blockIdx.x * 256 + threadIdx.x; i < N;
       i += (size_t)gridDim.x * 256)
    s += (double)fabsf(rs[i] - x[i]);
  for (int o = 32; o; o >>= 1) s += __shfl_down(s, o);
  __shared__ double wsum[4];
  if ((threadIdx.x & 63) == 0) wsum[threadIdx.x >> 6] = s;
  __syncthreads();
  if (threadIdx.x == 0) atomicAdd(acc, wsum[0] + wsum[1] + wsum[2] + wsum[3]);
}

__global__ void finalize_kernel(const double* __restrict__ acc,
                                const unsigned long long* __restrict__ cnt,
                                float* __restrict__ sr, float* __restrict__ err)
{
  if (threadIdx.x == 0) {
    sr[0] = (float)((double)cnt[0] / (512.0 * 64.0 * 2048.0));
    sr[1] = (float)((double)cnt[1] / (512.0 * 64.0 * 256.0));
    sr[2] = (float)((double)cnt[2] / (512.0 * 64.0 * 2048.0));
    err[0] = (float)(acc[0] / (512.0 * 64.0 * 1024.0));
  }
}

// ---------------------------------------------------------------------------
extern "C" void kernel_launch(void* const* d_in, const int* in_sizes, int n_in,
                              void* d_out, int out_size, void* d_ws, size_t ws_size,
                              hipStream_t stream) {
  const float* x    = (const float*)d_in[0];
  const float* Wenc = (const float*)d_in[1];
  const float* benc = (const float*)d_in[2];
  const float* Wlat = (const float*)d_in[3];
  const float* blat = (const float*)d_in[4];
  const float* Wdec = (const float*)d_in[5];
  const float* bdec = (const float*)d_in[6];
  const float* Wrec = (const float*)d_in[7];
  const float* brec = (const float*)d_in[8];

  float* out = (float*)d_out;
  float* recon     = out;
  float* recon_seq = out + 65536;
  float* latent    = recon_seq + (size_t)T_STEPS * BB * DD;
  float* sr        = latent + (size_t)T_STEPS * BB * LL;
  float* errp      = sr + 3;

  char* ws = (char*)d_ws;
  float* Ve = (float*)ws;                                   // 512 KB
  float* Vl = (float*)(ws + 524288);                        // 64 KB
  float* Vd = (float*)(ws + 589824);                        // 512 KB
  unsigned long long* cnt = (unsigned long long*)(ws + 1114112);  // 24 B
  double* errAcc = (double*)(ws + 1114136);                 // 8 B
  const size_t STATE = 1114368;

  unsigned char* Senc = (unsigned char*)(ws + STATE);       // 64 MB (Sdec overlaid)
  unsigned char* Sdec = Senc;
  const size_t Z_OFF    = STATE + 67108864;
  unsigned char* Z      = (unsigned char*)(ws + Z_OFF);     // 8 MB
  const size_t ILAT_OFF = Z_OFF + 8388608;
  float* Ilat           = (float*)(ws + ILAT_OFF);          // 32 MB
  const size_t ICH_OFF  = ILAT_OFF + 33554432;
  float* Ichunk         = (float*)(ws + ICH_OFF);           // Tc*512 KB

  int Tc = 512;
  while (Tc > 2 && ICH_OFF + (size_t)Tc * 524288 > ws_size) Tc >>= 1;

  hipMemsetAsync(ws, 0, STATE, stream);

  // Stage 1+2: encoder GEMM (K=1024, folds [512,512]) + Ve scan (FMA-LIF)
  for (int c0 = 0; c0 < T_STEPS; c0 += Tc) {
    gemm_panel<float><<<dim3(HH / 128, Tc * BB / 128), 256, 0, stream>>>(
        x + (size_t)c0 * BB * DD, Wenc, benc, Ichunk, Tc * BB, HH, DD);
    lif_scan<<<512, 256, 0, stream>>>(
        Ichunk, Ve, Senc + (size_t)c0 * BB * HH, nullptr, &cnt[0], Tc, BB * HH);
  }
  // Stage 3+4: latent GEMM (binary A, K=2048, folds [512x4]) + Vl scan
  gemm_panel<unsigned char><<<dim3(LL / 128, T_STEPS * BB / 128), 256, 0, stream>>>(
      Senc, Wlat, blat, Ilat, T_STEPS * BB, LL, HH);
  lif_scan<<<64, 256, 0, stream>>>(
      Ilat, Vl, Z, latent, &cnt[1], T_STEPS, BB * LL);
  // Stage 5+6+7: decoder GEMM (K=256, single panel) + Vd scan + recon GEMM
  for (int c0 = 0; c0 < T_STEPS; c0 += Tc) {
    gemm_panel<unsigned char><<<dim3(HH / 128, Tc * BB / 128), 256, 0, stream>>>(
        Z + (size_t)c0 * BB * LL, Wdec, bdec, Ichunk, Tc * BB, HH, LL);
    lif_scan<<<512, 256, 0, stream>>>(
        Ichunk, Vd, Sdec + (size_t)c0 * BB * HH, nullptr, &cnt[2], Tc, BB * HH);
    gemm_panel<unsigned char><<<dim3(DD / 128, Tc * BB / 128), 256, 0, stream>>>(
        Sdec + (size_t)c0 * BB * HH, Wrec, brec,
        recon_seq + (size_t)c0 * BB * DD, Tc * BB, DD, HH);
  }

  recon_mean_kernel<<<256, 256, 0, stream>>>(recon_seq, recon);
  err_kernel<<<2048, 256, 0, stream>>>(recon_seq, x, errAcc);
  finalize_kernel<<<1, 64, 0, stream>>>(errAcc, cnt, sr, errp);
}

// Round 26
// 4498.081 us; speedup vs baseline: 1.2750x; 1.0149x over previous
//
#include <hip/hip_runtime.h>

// T=512, B=64, D=1024, H=2048, L=256
// d_out (f32): recon[65536] | recon_seq[512*64*1024] | latent_seq[512*64*256] | spike_rate[3] | recon_err[1]
//
// VERIFIED reference model (r22 PASS): GEMMs = ascending-k fmaf chains,
// K-block 512, left-fold (one rounded add per boundary), bias separate f32
// add; LIF: V = fmaf(0.9, V, I); s = (V-1>0); V -= s.
// Round 26 (perf): r25 + double-buffered LDS, ONE barrier per k-tile.
// 128x128 tile, 8x8/thread, BK=16, single accumulator, RMW panel fold,
// conflict-free 4+4 split mapping.

#define T_STEPS 512
#define BB 64
#define DD 1024
#define HH 2048
#define LL 256

// ---------------------------------------------------------------------------
// Panel GEMM, KC=512, remainder-last, RMW left-fold: C = A@B + bias.
// A float or uchar(0/1). 128x128 tile, BK=16, 256 threads, 8x8 per thread.
// M%128==0, N%128==0, K%16==0 (K in {256,1024,2048}).
// ---------------------------------------------------------------------------
template<typename AT>
__global__ __launch_bounds__(256) void gemm_panel(
    const AT* __restrict__ A, const float* __restrict__ Bm,
    const float* __restrict__ bias, float* __restrict__ C,
    int M, int N, int K)
{
  __shared__ float As[2][16][128];
  __shared__ float Bs[2][16][128];
  const int tid = threadIdx.x;
  const int tx = tid & 15, ty = tid >> 4;
  const int row0 = blockIdx.y * 128, col0 = blockIdx.x * 128;
  const int lar = tid >> 1;              // A row 0..127
  const int lak = (tid & 1) * 8;         // A k-offset 0 or 8
  const int lbk = tid >> 4;              // B k-row 0..15
  const int lbn = (tid & 15) * 8;        // B col 0,8,...,120

  float pacc[8][8] = {};                 // current panel (ascending-k chain)
  const int KT = K >> 4;
  int panel = 0;

  float a8[8];
  float4 b40, b41;
  auto fetch = [&](int kt) {
    if constexpr (sizeof(AT) == 1) {
      unsigned long long w =
          *(const unsigned long long*)(A + (size_t)(row0 + lar) * K + kt * 16 + lak);
      #pragma unroll
      for (int j = 0; j < 8; ++j) a8[j] = (float)((w >> (8 * j)) & 0xFFull);
    } else {
      const float* ap = (const float*)A + (size_t)(row0 + lar) * K + kt * 16 + lak;
      float4 f0 = *(const float4*)ap;
      float4 f1 = *(const float4*)(ap + 4);
      a8[0] = f0.x; a8[1] = f0.y; a8[2] = f0.z; a8[3] = f0.w;
      a8[4] = f1.x; a8[5] = f1.y; a8[6] = f1.z; a8[7] = f1.w;
    }
    const float* bp = Bm + (size_t)(kt * 16 + lbk) * N + col0 + lbn;
    b40 = *(const float4*)bp;
    b41 = *(const float4*)(bp + 4);
  };

  // flush current panel into C (exact left-fold; bias on last flush)
  auto flush = [&](bool last) {
    #pragma unroll
    for (int i = 0; i < 8; ++i) {
      const int r = (i < 4) ? (ty * 4 + i) : (64 + ty * 4 + (i - 4));
      float* cp = C + (size_t)(row0 + r) * N + col0;
      float o[8];
      if (panel == 0) {
        #pragma unroll
        for (int j = 0; j < 8; ++j) o[j] = pacc[i][j];
      } else {
        float4 c0 = *(const float4*)(cp + tx * 4);
        float4 c1 = *(const float4*)(cp + 64 + tx * 4);
        o[0] = __fadd_rn(c0.x, pacc[i][0]); o[1] = __fadd_rn(c0.y, pacc[i][1]);
        o[2] = __fadd_rn(c0.z, pacc[i][2]); o[3] = __fadd_rn(c0.w, pacc[i][3]);
        o[4] = __fadd_rn(c1.x, pacc[i][4]); o[5] = __fadd_rn(c1.y, pacc[i][5]);
        o[6] = __fadd_rn(c1.z, pacc[i][6]); o[7] = __fadd_rn(c1.w, pacc[i][7]);
      }
      if (last) {
        float4 s0 = *(const float4*)&bias[col0 + tx * 4];
        float4 s1 = *(const float4*)&bias[col0 + 64 + tx * 4];
        o[0] = __fadd_rn(o[0], s0.x); o[1] = __fadd_rn(o[1], s0.y);
        o[2] = __fadd_rn(o[2], s0.z); o[3] = __fadd_rn(o[3], s0.w);
        o[4] = __fadd_rn(o[4], s1.x); o[5] = __fadd_rn(o[5], s1.y);
        o[6] = __fadd_rn(o[6], s1.z); o[7] = __fadd_rn(o[7], s1.w);
      }
      *(float4*)(cp + tx * 4) = *(const float4*)&o[0];
      *(float4*)(cp + 64 + tx * 4) = *(const float4*)&o[4];
      if (!last) {
        #pragma unroll
        for (int j = 0; j < 8; ++j) pacc[i][j] = 0.0f;
      }
    }
    ++panel;
  };

  fetch(0);
  for (int kt = 0; kt < KT; ++kt) {
    const int cur = kt & 1;
    if (kt > 0 && (kt & 31) == 0) flush(false);   // k%512 boundary
    // stage tile kt (regs from previous fetch) into buf[cur]
    #pragma unroll
    for (int j = 0; j < 8; ++j) As[cur][lak + j][lar] = a8[j];
    *(float4*)&Bs[cur][lbk][lbn] = b40;
    *(float4*)&Bs[cur][lbk][lbn + 4] = b41;
    __syncthreads();          // single barrier per tile:
                              // - buf[cur] writes visible for this compute
                              // - all waves' compute(kt-1) on buf[cur^1] done
                              //   before next iteration stages into it
    if (kt + 1 < KT) fetch(kt + 1);
    #pragma unroll
    for (int k = 0; k < 16; ++k) {       // global k ascending within panel
      float av[8], bv[8];
      *(float4*)&av[0] = *(const float4*)&As[cur][k][ty * 4];      // broadcast
      *(float4*)&av[4] = *(const float4*)&As[cur][k][64 + ty * 4];
      *(float4*)&bv[0] = *(const float4*)&Bs[cur][k][tx * 4];      // <=2-way
      *(float4*)&bv[4] = *(const float4*)&Bs[cur][k][64 + tx * 4];
      #pragma unroll
      for (int i = 0; i < 8; ++i)
        #pragma unroll
        for (int j = 0; j < 8; ++j)
          pacc[i][j] = fmaf(av[i], bv[j], pacc[i][j]);
    }
  }
  flush(true);
}

// ---------------------------------------------------------------------------
// Elementwise LIF scan: v = fma(0.9f, v, I); s = (v-1>0); v -= s.
// ---------------------------------------------------------------------------
__global__ __launch_bounds__(256) void lif_scan(
    const float* __restrict__ I, float* __restrict__ V,
    unsigned char* __restrict__ S, float* __restrict__ latent,
    unsigned long long* __restrict__ cnt, int Tc, int NTOT)
{
  const int idx = blockIdx.x * 256 + threadIdx.x;
  float v = V[idx];
  unsigned c = 0;
  for (int t = 0; t < Tc; ++t) {
    v = fmaf(0.9f, v, I[(size_t)t * NTOT + idx]);   // single rounding
    const bool s = __fsub_rn(v, 1.0f) > 0.0f;
    if (s) v = __fsub_rn(v, 1.0f);
    S[(size_t)t * NTOT + idx] = (unsigned char)s;
    if (latent) latent[(size_t)t * NTOT + idx] = s ? 1.0f : 0.0f;
    c += (unsigned)s;
  }
  V[idx] = v;
  unsigned long long cc = c;
  for (int o = 32; o; o >>= 1) cc += __shfl_down(cc, o);
  if ((threadIdx.x & 63) == 0 && cc) atomicAdd(cnt, cc);
}

// ---------------------------------------------------------------------------
__global__ __launch_bounds__(256) void recon_mean_kernel(
    const float* __restrict__ rs, float* __restrict__ out)
{
  const int idx = blockIdx.x * 256 + threadIdx.x;   // 65536 total
  double s = 0.0;
  for (int t = 0; t < T_STEPS; ++t) s += (double)rs[(size_t)t * 65536 + idx];
  out[idx] = (float)(s * (1.0 / 512.0));
}

__global__ __launch_bounds__(256) void err_kernel(
    const float* __restrict__ rs, const float* __restrict__ x,
    double* __restrict__ acc)
{
  const size_t N = (size_t)T_STEPS * BB * DD;
  double s = 0.0;
  for (size_t i = (size_t)blockIdx.x * 256 + threadIdx.x; i < N;
       i += (size_t)gridDim.x * 256)
    s += (double)fabsf(rs[i] - x[i]);
  for (int o = 32; o; o >>= 1) s += __shfl_down(s, o);
  __shared__ double wsum[4];
  if ((threadIdx.x & 63) == 0) wsum[threadIdx.x >> 6] = s;
  __syncthreads();
  if (threadIdx.x == 0) atomicAdd(acc, wsum[0] + wsum[1] + wsum[2] + wsum[3]);
}

__global__ void finalize_kernel(const double* __restrict__ acc,
                                const unsigned long long* __restrict__ cnt,
                                float* __restrict__ sr, float* __restrict__ err)
{
  if (threadIdx.x == 0) {
    sr[0] = (float)((double)cnt[0] / (512.0 * 64.0 * 2048.0));
    sr[1] = (float)((double)cnt[1] / (512.0 * 64.0 * 256.0));
    sr[2] = (float)((double)cnt[2] / (512.0 * 64.0 * 2048.0));
    err[0] = (float)(acc[0] / (512.0 * 64.0 * 1024.0));
  }
}

// ---------------------------------------------------------------------------
extern "C" void kernel_launch(void* const* d_in, const int* in_sizes, int n_in,
                              void* d_out, int out_size, void* d_ws, size_t ws_size,
                              hipStream_t stream) {
  const float* x    = (const float*)d_in[0];
  const float* Wenc = (const float*)d_in[1];
  const float* benc = (const float*)d_in[2];
  const float* Wlat = (const float*)d_in[3];
  const float* blat = (const float*)d_in[4];
  const float* Wdec = (const float*)d_in[5];
  const float* bdec = (const float*)d_in[6];
  const float* Wrec = (const float*)d_in[7];
  const float* brec = (const float*)d_in[8];

  float* out = (float*)d_out;
  float* recon     = out;
  float* recon_seq = out + 65536;
  float* latent    = recon_seq + (size_t)T_STEPS * BB * DD;
  float* sr        = latent + (size_t)T_STEPS * BB * LL;
  float* errp      = sr + 3;

  char* ws = (char*)d_ws;
  float* Ve = (float*)ws;                                   // 512 KB
  float* Vl = (float*)(ws + 524288);                        // 64 KB
  float* Vd = (float*)(ws + 589824);                        // 512 KB
  unsigned long long* cnt = (unsigned long long*)(ws + 1114112);  // 24 B
  double* errAcc = (double*)(ws + 1114136);                 // 8 B
  const size_t STATE = 1114368;

  unsigned char* Senc = (unsigned char*)(ws + STATE);       // 64 MB (Sdec overlaid)
  unsigned char* Sdec = Senc;
  const size_t Z_OFF    = STATE + 67108864;
  unsigned char* Z      = (unsigned char*)(ws + Z_OFF);     // 8 MB
  const size_t ILAT_OFF = Z_OFF + 8388608;
  float* Ilat           = (float*)(ws + ILAT_OFF);          // 32 MB
  const size_t ICH_OFF  = ILAT_OFF + 33554432;
  float* Ichunk         = (float*)(ws + ICH_OFF);           // Tc*512 KB

  int Tc = 512;
  while (Tc > 2 && ICH_OFF + (size_t)Tc * 524288 > ws_size) Tc >>= 1;

  hipMemsetAsync(ws, 0, STATE, stream);

  // Stage 1+2: encoder GEMM (K=1024, folds [512,512]) + Ve scan (FMA-LIF)
  for (int c0 = 0; c0 < T_STEPS; c0 += Tc) {
    gemm_panel<float><<<dim3(HH / 128, Tc * BB / 128), 256, 0, stream>>>(
        x + (size_t)c0 * BB * DD, Wenc, benc, Ichunk, Tc * BB, HH, DD);
    lif_scan<<<512, 256, 0, stream>>>(
        Ichunk, Ve, Senc + (size_t)c0 * BB * HH, nullptr, &cnt[0], Tc, BB * HH);
  }
  // Stage 3+4: latent GEMM (binary A, K=2048, folds [512x4]) + Vl scan
  gemm_panel<unsigned char><<<dim3(LL / 128, T_STEPS * BB / 128), 256, 0, stream>>>(
      Senc, Wlat, blat, Ilat, T_STEPS * BB, LL, HH);
  lif_scan<<<64, 256, 0, stream>>>(
      Ilat, Vl, Z, latent, &cnt[1], T_STEPS, BB * LL);
  // Stage 5+6+7: decoder GEMM (K=256, single panel) + Vd scan + recon GEMM
  for (int c0 = 0; c0 < T_STEPS; c0 += Tc) {
    gemm_panel<unsigned char><<<dim3(HH / 128, Tc * BB / 128), 256, 0, stream>>>(
        Z + (size_t)c0 * BB * LL, Wdec, bdec, Ichunk, Tc * BB, HH, LL);
    lif_scan<<<512, 256, 0, stream>>>(
        Ichunk, Vd, Sdec + (size_t)c0 * BB * HH, nullptr, &cnt[2], Tc, BB * HH);
    gemm_panel<unsigned char><<<dim3(DD / 128, Tc * BB / 128), 256, 0, stream>>>(
        Sdec + (size_t)c0 * BB * HH, Wrec, brec,
        recon_seq + (size_t)c0 * BB * DD, Tc * BB, DD, HH);
  }

  recon_mean_kernel<<<256, 256, 0, stream>>>(recon_seq, recon);
  err_kernel<<<2048, 256, 0, stream>>>(recon_seq, x, errAcc);
  finalize_kernel<<<1, 64, 0, stream>>>(errAcc, cnt, sr, errp);
}